// Round 11
// baseline (142.424 us; speedup 1.0000x reference)
//
#include <hip/hip_runtime.h>

// Bilinear backward warp: img [B,C,H,W] f32, flo [B,2,H,W] f32 -> out [B,C,H,W] f32
// B=8, C=64, H=256, W=448
//
// R11: small-block deep pipeline.
//  - 256-thread (4-wave) blocks, ONE pixel per thread (4 rows x 64 cols tile).
//  - 8 rotating LDS buffers (10 rows x 72 cols band each, 23KB total)
//    -> 7 resident blocks/CU (28 waves) for cross-block stall coverage.
//  - depth-3 prefetch: at round k (channels m,m+1) stage channels m+6,m+7.
//  - raw s_barrier + EXACT counted s_waitcnt vmcnt(N): each wave issues
//    exactly 1 global_load_lds per channel (180 words, lanes<45) and 2 stores
//    per round, so steady-state younger-than-target = 10.
//    (R4/R5's counted-vmcnt failures were miscounted stores, not the idea.)

#define BN 8
#define CN 64
#define HN 256
#define WN 448
#define HW (HN * WN)
#define R 4               // output rows per block
#define BAND 10           // staged rows: lo = h0-3 .. h0+6
#define COLS 64           // output cols per block
#define LCOLS 72          // staged cols (halo 4 each side)
#define BWORDS (BAND * LCOLS)   // 720 words
#define BSTRIDE 724             // +4 pad words (sA+1 read at last word)
#define NBUF 8
#define TPB 256           // 4 waves
#define NXCD 8
#define ROUNDS (CN / 2)   // 32 rounds of 2 channels

typedef __attribute__((address_space(1))) const void glb_v;
typedef __attribute__((address_space(3))) void lds_v;

__global__ __launch_bounds__(TPB) void warp_kernel(const float* __restrict__ img,
                                                   const float* __restrict__ flo,
                                                   float* __restrict__ out) {
    __shared__ float lds[NBUF][BSTRIDE];   // 8 x 2896 B = 23168 B

    // XCD swizzle: 3584 blocks = 448/XCD = one batch per XCD; consecutive
    // wgids are col-tiles of the same row band -> share L2 rows.
    const int nwg = gridDim.x;            // 3584
    const int cpx = nwg / NXCD;           // 448
    const int bid = blockIdx.x;
    const int wgid = (bid % NXCD) * cpx + (bid / NXCD);

    const int b       = wgid / cpx;       // 0..7
    const int rem     = wgid % cpx;       // 0..447
    const int rowtile = rem / 7;          // 0..63
    const int ct      = rem % 7;          // 0..6
    const int h0      = rowtile * R;
    const int c0      = ct * COLS;

    const int t    = threadIdx.x;
    const int wv   = t >> 6;              // 0..3
    const int lane = t & 63;
    const int row  = wv;                  // thread's output row 0..3
    const int col  = lane;                // thread's output col 0..63

    int lo = h0 - 3;
    lo = lo < 0 ? 0 : (lo > HN - BAND ? HN - BAND : lo);
    int bc = c0 - 4;
    bc = bc < 0 ? 0 : (bc > WN - LCOLS ? WN - LCOLS : bc);

    const float* imgb = img + (size_t)b * CN * HW;
    const float* flob = flo + (size_t)b * 2 * HW;

    // ---- per-pixel setup (single pixel per thread) ----
    const int h = h0 + row;
    const int w = c0 + col;
    const int hw = h * WN + w;
    const float fx = flob[hw];
    const float fy = flob[HW + hw];
    const float x = (float)w + fx;
    const float y = (float)h + fy;
    int x0 = (int)x;                 // trunc toward zero (matches ref)
    int x1 = x0 + 1;
    int y0 = (int)y;
    int y1 = y0 + 1;
    x0 = min(max(x0, 0), WN - 1);
    x1 = min(max(x1, 0), WN - 1);
    y0 = min(max(y0, 0), HN - 1);
    y1 = min(max(y1, 0), HN - 1);
    const float x0f = (float)x0, x1f = (float)x1;
    const float y0f = (float)y0, y1f = (float)y1;
    const float wa = (x1f - x) * (y1f - y);
    const float wb = (x1f - x) * (y - y0f);
    const float wc = (x - x0f) * (y1f - y);
    const float wd = (x - x0f) * (y - y0f);
    const int dx = x1 - x0;          // 0 only at l/r edge clip
    const bool oky = (y0 >= lo) && (y1 <= lo + BAND - 1);
    const bool okx = (x0 >= bc) && ((x0 - bc) + dx <= LCOLS - 1);
    const bool fb = !(oky && okx);
    const bool dirty = __any(fb);    // wave-uniform, ~15% of waves
    const int rA = min(max(y0 - lo, 0), BAND - 1);
    const int rB = min(max(y1 - lo, 0), BAND - 1);
    const int cx = min(max(x0 - bc, 0), LCOLS - 1);
    const int sA = rA * LCOLS + cx;  // <= 719; +1 read covered by pad
    const int sB = rB * LCOLS + cx;
    const int gA = y0 * WN + x0;
    const int gB = y1 * WN + x0;

    // ---- staging geometry: band = 720 words = 180 x 16B chunks, 45/wave ----
    // chunk q = wv*45 + lane (lane<45): row = q/18, colword = (q%18)*4.
    // 72 % 4 == 0 so a 16B chunk never crosses a band-row boundary.
    const int q = wv * 45 + lane;
    const int qr = q / 18;
    const int srcoff = qr * WN + (q - qr * 18) * 4;   // band-relative global words
    char* const dstbase = (char*)&lds[0][0] + wv * 720;  // + bufi*2896 later

    auto stage = [&](int bufi, int c) {   // 1 global_load_lds per wave
        if (lane < 45) {
            const float* g = imgb + (size_t)c * HW + (size_t)lo * WN + bc + srcoff;
            __builtin_amdgcn_global_load_lds((glb_v*)g,
                (lds_v*)(dstbase + bufi * (BSTRIDE * 4)), 16, 0, 0);
        }
    };

    // prologue: stage channels 0..5 (6 instrs); wait ch0,1 (younger=4)
    stage(0, 0); stage(1, 1); stage(2, 2); stage(3, 3); stage(4, 4); stage(5, 5);
    asm volatile("s_waitcnt vmcnt(4)" ::: "memory");
    __builtin_amdgcn_s_barrier();

    float* const outp = out + (size_t)b * CN * HW + (size_t)h * WN + w;

    for (int k = 0; k < ROUNDS; ++k) {
        const int m = 2 * k;
        if (k <= 28) {                    // stage channels m+6, m+7 (depth 3 rounds)
            stage((m + 6) & 7, m + 6);
            stage((m + 7) & 7, m + 7);
        }

        const float* bufA = &lds[m & 7][0];
        const float* bufB = &lds[(m + 1) & 7][0];
        float oA, oB;
        if (!dirty) {
            const float Aa0 = bufA[sA];
            const float Aa1 = bufA[sA + 1];   // ds_read2_b32 pair
            const float Ab0 = bufA[sB];
            const float Ab1 = bufA[sB + 1];
            const float Ba0 = bufB[sA];
            const float Ba1 = bufB[sA + 1];
            const float Bb0 = bufB[sB];
            const float Bb1 = bufB[sB + 1];
            const float AIc = dx ? Aa1 : Aa0;
            const float AId = dx ? Ab1 : Ab0;
            const float BIc = dx ? Ba1 : Ba0;
            const float BId = dx ? Bb1 : Bb0;
            oA = wa * Aa0 + wb * Ab0 + wc * AIc + wd * AId;
            oB = wa * Ba0 + wb * Bb0 + wc * BIc + wd * BId;
        } else {
            const float* pgA = imgb + (size_t)m * HW;
            const float* pgB = pgA + HW;
            float Aa0 = bufA[sA];
            float Aa1 = bufA[sA + 1];
            float Ab0 = bufA[sB];
            float Ab1 = bufA[sB + 1];
            float Ba0 = bufB[sA];
            float Ba1 = bufB[sA + 1];
            float Bb0 = bufB[sB];
            float Bb1 = bufB[sB + 1];
            if (fb) {
                Aa0 = pgA[gA]; Aa1 = pgA[gA + dx];
                Ab0 = pgA[gB]; Ab1 = pgA[gB + dx];
                Ba0 = pgB[gA]; Ba1 = pgB[gA + dx];
                Bb0 = pgB[gB]; Bb1 = pgB[gB + dx];
            }
            const float AIc = dx ? Aa1 : Aa0;
            const float AId = dx ? Ab1 : Ab0;
            const float BIc = dx ? Ba1 : Ba0;
            const float BId = dx ? Bb1 : Bb0;
            oA = wa * Aa0 + wb * Ab0 + wc * AIc + wd * AId;
            oB = wa * Ba0 + wb * Bb0 + wc * BIc + wd * BId;
        }
        outp[(size_t)m * HW] = oA;
        outp[(size_t)(m + 1) * HW] = oB;

        if (k < ROUNDS - 1) {
            // Per-wave FIFO wait: guarantee stage(m+2,m+3) retired.
            // younger-than-target (clean wave): k=0 -> 6, k=1 -> 8,
            // 2<=k<=28 -> 10, k=29 -> 8, k=30 -> 6. Dirty-wave fallback
            // loads only strengthen the wait (correct).
            if (k == 0) {
                asm volatile("s_waitcnt vmcnt(6)" ::: "memory");
            } else if (k == 1) {
                asm volatile("s_waitcnt vmcnt(8)" ::: "memory");
            } else if (k <= 28) {
                asm volatile("s_waitcnt vmcnt(10)" ::: "memory");
            } else if (k == 29) {
                asm volatile("s_waitcnt vmcnt(8)" ::: "memory");
            } else {
                asm volatile("s_waitcnt vmcnt(6)" ::: "memory");
            }
            __builtin_amdgcn_s_barrier();
        }
    }
}

extern "C" void kernel_launch(void* const* d_in, const int* in_sizes, int n_in,
                              void* d_out, int out_size, void* d_ws, size_t ws_size,
                              hipStream_t stream) {
    const float* img = (const float*)d_in[0];
    const float* flo = (const float*)d_in[1];
    float* out = (float*)d_out;

    const int grid = BN * (HN / R) * (WN / COLS);   // 8*64*7 = 3584
    warp_kernel<<<grid, TPB, 0, stream>>>(img, flo, out);
}

// Round 12
// 124.300 us; speedup vs baseline: 1.1458x; 1.1458x over previous
//
#include <hip/hip_runtime.h>

// Bilinear backward warp: img [B,C,H,W] f32, flo [B,2,H,W] f32 -> out [B,C,H,W] f32
// B=8, C=64, H=256, W=448
//
// R12 = R7's champion skeleton (448 threads, 2 channels/round, 16 rounds,
// __syncthreads-only sync, in-loop rare fallback) with channel-PAIR
// interleaved LDS staging:
//  - LDS buffer holds band position p as float2 (ch m, ch m+1) -> one
//    ds_read2_b64 per tap row returns 2ch x {x0,x1}: DS-read instrs and
//    conflict events halve vs R7 (conflicts were ~20us/CU, ~= DS busy time).
//  - bank = 2*x0 mod 32 (row term 896 vanishes mod 128): lane-consecutive,
//    ~2-way = free.
//  - staging is reg-staged (global_load_lds can't interleave): 20 coalesced
//    dword loads issued at round TOP (latency hides under compute), 10
//    ds_write_b64 at round bottom; compiler inserts the waits. No asm.

#define BN 8
#define CN 64
#define HN 256
#define WN 448
#define HW (HN * WN)
#define R 4              // output rows per block
#define BAND 10          // staged img rows per channel (lo = h0-3)
#define BWORDS (BAND * WN)    // 4480 positions per band
#define TPB WN           // 448 threads = 7 waves
#define NXCD 8
#define CSPLIT 2
#define CLOOP (CN / CSPLIT)   // 32 channels per block
#define ROUNDS (CLOOP / 2)    // 16 rounds of 2 channels (one pair)
#define CHUNKS 10             // BWORDS / TPB == 10 exactly

typedef __attribute__((address_space(1))) const void glb_v;
typedef __attribute__((address_space(3))) void lds_v;

__global__ __launch_bounds__(TPB) void warp_kernel(const float* __restrict__ img,
                                                   const float* __restrict__ flo,
                                                   float* __restrict__ out) {
    // 2 buffers x (2*4480 + 4) floats = 71744 B -> 2 blocks/CU
    __shared__ float lds[2][2 * BWORDS + 4];

    // XCD swizzle: 1024 blocks = 128/XCD = one batch per XCD.
    const int nwg = gridDim.x;            // 1024
    const int cpx = nwg / NXCD;           // 128
    const int bid = blockIdx.x;
    const int wgid = (bid % NXCD) * cpx + (bid / NXCD);

    const int b    = wgid / cpx;          // 0..7
    const int rem  = wgid % cpx;          // 0..127
    const int tile = rem >> 1;            // 0..63
    const int ch0  = (rem & 1) * CLOOP;   // 0 or 32
    const int h0   = tile * R;
    const int w    = threadIdx.x;         // 0..447

    int lo = h0 - 3;
    lo = lo < 0 ? 0 : (lo > HN - BAND ? HN - BAND : lo);

    const float* imgb = img + (size_t)b * CN * HW;
    const float* flob = flo + (size_t)b * 2 * HW;

    // ---- per-pixel setup, channel-invariant ----
    float wa[R], wb[R], wc[R], wd[R];
    int sA[R], sB[R];       // band positions (row-clamped)
    int gA[R], gB[R];       // plane-relative global word offsets (fallback)
    int dx_[R];
    bool fb[R];
    bool anyfb = false;
#pragma unroll
    for (int r = 0; r < R; ++r) {
        const int h = h0 + r;
        const int hw = h * WN + w;
        const float fx = flob[hw];
        const float fy = flob[HW + hw];
        const float x = (float)w + fx;
        const float y = (float)h + fy;
        int x0 = (int)x;                 // trunc toward zero (matches ref)
        int x1 = x0 + 1;
        int y0 = (int)y;
        int y1 = y0 + 1;
        x0 = min(max(x0, 0), WN - 1);
        x1 = min(max(x1, 0), WN - 1);
        y0 = min(max(y0, 0), HN - 1);
        y1 = min(max(y1, 0), HN - 1);
        const float x0f = (float)x0, x1f = (float)x1;
        const float y0f = (float)y0, y1f = (float)y1;
        wa[r] = (x1f - x) * (y1f - y);
        wb[r] = (x1f - x) * (y - y0f);
        wc[r] = (x - x0f) * (y1f - y);
        wd[r] = (x - x0f) * (y - y0f);
        dx_[r] = x1 - x0;                // 0 only at l/r edge clip
        const bool inband = (y0 >= lo) && (y1 <= lo + BAND - 1);
        fb[r] = !inband;
        anyfb |= fb[r];
        const int rA = min(max(y0 - lo, 0), BAND - 1);
        const int rB = min(max(y1 - lo, 0), BAND - 1);
        sA[r] = rA * WN + x0;            // band position
        sB[r] = rB * WN + x0;
        gA[r] = y0 * WN + x0;
        gB[r] = y1 * WN + x0;
    }
    const bool dirty = __any(anyfb);    // wave-uniform, rare

    const int t = threadIdx.x;

    // ---- reg-staged loads: band is contiguous (lo*WN .. +4480) in each plane;
    //      thread t owns positions j*448+t, j=0..9 (coalesced 256B per instr) ----
    float ga[CHUNKS], gb[CHUNKS];
    auto stage_load = [&](int c) {       // c = global channel (even of pair)
        const float* pA = imgb + (size_t)c * HW + (size_t)lo * WN + t;
        const float* pB = pA + HW;
#pragma unroll
        for (int j = 0; j < CHUNKS; ++j) {
            ga[j] = pA[j * WN];
            gb[j] = pB[j * WN];
        }
    };
    auto stage_write = [&](int bufi) {
        float2* dst = (float2*)&lds[bufi][0];
#pragma unroll
        for (int j = 0; j < CHUNKS; ++j) {
            dst[j * WN + t] = make_float2(ga[j], gb[j]);   // ds_write_b64
        }
    };

    // prologue: pair 0
    stage_load(ch0);
    stage_write(0);
    __syncthreads();

    float* outp = out + (size_t)b * CN * HW + (size_t)ch0 * HW + (size_t)h0 * WN + w;

    for (int k = 0; k < ROUNDS; ++k) {
        const int m = 2 * k;             // local channel pair (m, m+1)
        if (k + 1 < ROUNDS) stage_load(ch0 + m + 2);   // issue early: hides under compute

        const float* buf = &lds[k & 1][0];
        float oA[R], oB[R];
        if (!dirty) {
#pragma unroll
            for (int r = 0; r < R; ++r) {
                const float2 a01 = *(const float2*)&buf[2 * sA[r]];       // (A@x0, B@x0)
                const float2 a23 = *(const float2*)&buf[2 * sA[r] + 2];   // (A@x1, B@x1)
                const float2 b01 = *(const float2*)&buf[2 * sB[r]];
                const float2 b23 = *(const float2*)&buf[2 * sB[r] + 2];
                const float AIc = dx_[r] ? a23.x : a01.x;
                const float AId = dx_[r] ? b23.x : b01.x;
                const float BIc = dx_[r] ? a23.y : a01.y;
                const float BId = dx_[r] ? b23.y : b01.y;
                oA[r] = wa[r] * a01.x + wb[r] * b01.x + wc[r] * AIc + wd[r] * AId;
                oB[r] = wa[r] * a01.y + wb[r] * b01.y + wc[r] * BIc + wd[r] * BId;
            }
        } else {
            const float* pgA = imgb + (size_t)(ch0 + m) * HW;
            const float* pgB = pgA + HW;
#pragma unroll
            for (int r = 0; r < R; ++r) {
                float2 a01 = *(const float2*)&buf[2 * sA[r]];
                float2 a23 = *(const float2*)&buf[2 * sA[r] + 2];
                float2 b01 = *(const float2*)&buf[2 * sB[r]];
                float2 b23 = *(const float2*)&buf[2 * sB[r] + 2];
                if (fb[r]) {
                    a01.x = pgA[gA[r]];  a23.x = pgA[gA[r] + dx_[r]];
                    b01.x = pgA[gB[r]];  b23.x = pgA[gB[r] + dx_[r]];
                    a01.y = pgB[gA[r]];  a23.y = pgB[gA[r] + dx_[r]];
                    b01.y = pgB[gB[r]];  b23.y = pgB[gB[r] + dx_[r]];
                }
                const float AIc = dx_[r] ? a23.x : a01.x;
                const float AId = dx_[r] ? b23.x : b01.x;
                const float BIc = dx_[r] ? a23.y : a01.y;
                const float BId = dx_[r] ? b23.y : b01.y;
                oA[r] = wa[r] * a01.x + wb[r] * b01.x + wc[r] * AIc + wd[r] * AId;
                oB[r] = wa[r] * a01.y + wb[r] * b01.y + wc[r] * BIc + wd[r] * BId;
            }
        }
#pragma unroll
        for (int r = 0; r < R; ++r) {
            outp[(size_t)m * HW + r * WN] = oA[r];
            outp[(size_t)(m + 1) * HW + r * WN] = oB[r];
        }

        if (k + 1 < ROUNDS) stage_write((k + 1) & 1);  // compiler waits loads here
        __syncthreads();
    }
}

extern "C" void kernel_launch(void* const* d_in, const int* in_sizes, int n_in,
                              void* d_out, int out_size, void* d_ws, size_t ws_size,
                              hipStream_t stream) {
    const float* img = (const float*)d_in[0];
    const float* flo = (const float*)d_in[1];
    float* out = (float*)d_out;

    const int grid = BN * (HN / R) * CSPLIT;   // 1024 blocks
    warp_kernel<<<grid, TPB, 0, stream>>>(img, flo, out);
}

// Round 13
// 110.056 us; speedup vs baseline: 1.2941x; 1.1294x over previous
//
#include <hip/hip_runtime.h>

// Bilinear backward warp: img [B,C,H,W] f32, flo [B,2,H,W] f32 -> out [B,C,H,W] f32
// B=8, C=64, H=256, W=448
//
// R13 = R7 (champion: 448t, 4 rotating LDS bands, 2 channels/round, 16 rounds,
// __syncthreads-only, in-loop rare fallback) + ONE change: round k's outputs
// are held in registers across the barrier and stored at the TOP of round k+1
// (after the stage issue, before DS reads). At every barrier the youngest VMEM
// ops are then a full round (~2.5us) old -> the __syncthreads vmcnt(0) drain
// retires instantly. Previously the 8 stores issued immediately before each
// barrier put a store-retire round-trip on every round's critical path.

#define BN 8
#define CN 64
#define HN 256
#define WN 448
#define HW (HN * WN)
#define R 4              // output rows per block
#define BAND 10          // staged img rows per channel (lo = h0-3)
#define TPB WN           // 448 threads = 7 waves
#define NXCD 8
#define CSPLIT 2
#define CLOOP (CN / CSPLIT)   // 32 channels per block
#define ROUNDS (CLOOP / 2)    // 16 rounds of 2 channels

typedef __attribute__((address_space(1))) const void glb_v;
typedef __attribute__((address_space(3))) void lds_v;

__global__ __launch_bounds__(TPB) void warp_kernel(const float* __restrict__ img,
                                                   const float* __restrict__ flo,
                                                   float* __restrict__ out) {
    // 4 buffers x (4480+4) floats = 71744 B -> 2 blocks/CU
    __shared__ float lds[4][BAND * WN + 4];

    // XCD swizzle: 1024 blocks = 128/XCD = one batch per XCD; adjacent wgids
    // are the two channel-halves of the same tile -> share L2 row bands.
    const int nwg = gridDim.x;            // 1024
    const int cpx = nwg / NXCD;           // 128
    const int bid = blockIdx.x;
    const int wgid = (bid % NXCD) * cpx + (bid / NXCD);

    const int b    = wgid / cpx;          // 0..7
    const int rem  = wgid % cpx;          // 0..127
    const int tile = rem >> 1;            // 0..63
    const int ch0  = (rem & 1) * CLOOP;   // 0 or 32
    const int h0   = tile * R;
    const int w    = threadIdx.x;         // 0..447

    int lo = h0 - 3;
    lo = lo < 0 ? 0 : (lo > HN - BAND ? HN - BAND : lo);

    const float* imgb = img + (size_t)b * CN * HW;
    const float* flob = flo + (size_t)b * 2 * HW;

    // ---- per-pixel setup, channel-invariant ----
    float wa[R], wb[R], wc[R], wd[R];
    int sA[R], sB[R];       // band-relative LDS word offsets
    int gA[R], gB[R];       // plane-relative global word offsets (fallback)
    int dx_[R];
    bool fb[R];
    bool anyfb = false;
#pragma unroll
    for (int r = 0; r < R; ++r) {
        const int h = h0 + r;
        const int hw = h * WN + w;
        const float fx = flob[hw];
        const float fy = flob[HW + hw];
        const float x = (float)w + fx;
        const float y = (float)h + fy;
        int x0 = (int)x;                 // trunc toward zero (matches ref)
        int x1 = x0 + 1;
        int y0 = (int)y;
        int y1 = y0 + 1;
        x0 = min(max(x0, 0), WN - 1);
        x1 = min(max(x1, 0), WN - 1);
        y0 = min(max(y0, 0), HN - 1);
        y1 = min(max(y1, 0), HN - 1);
        const float x0f = (float)x0, x1f = (float)x1;
        const float y0f = (float)y0, y1f = (float)y1;
        wa[r] = (x1f - x) * (y1f - y);
        wb[r] = (x1f - x) * (y - y0f);
        wc[r] = (x - x0f) * (y1f - y);
        wd[r] = (x - x0f) * (y - y0f);
        dx_[r] = x1 - x0;                // 0 only at l/r edge clip
        const bool inband = (y0 >= lo) && (y1 <= lo + BAND - 1);
        fb[r] = !inband;
        anyfb |= fb[r];
        const int rA = min(max(y0 - lo, 0), BAND - 1);
        const int rB = min(max(y1 - lo, 0), BAND - 1);
        sA[r] = rA * WN + x0;
        sB[r] = rB * WN + x0;
        gA[r] = y0 * WN + x0;
        gB[r] = y1 * WN + x0;
    }
    const bool dirty = __any(anyfb);    // wave-uniform, rare

    const int wave = threadIdx.x >> 6;   // 0..6
    const int lane = threadIdx.x & 63;

    // ---- staging: 10 rows x 448 = 4480 words = 17x1KB chunks + 2x256B tails ----
    auto stage = [&](int bufi, int c) {          // c = global channel
        const float* src = imgb + (size_t)c * HW + (size_t)lo * WN;
        float* dst = &lds[bufi][0];
        for (int s = wave; s < 17; s += 7) {
            __builtin_amdgcn_global_load_lds(
                (glb_v*)(src + s * 256 + lane * 4),
                (lds_v*)(dst + s * 256), 16, 0, 0);
        }
        if (wave < 2) {
            const int base = 17 * 256 + wave * 64;
            __builtin_amdgcn_global_load_lds(
                (glb_v*)(src + base + lane),
                (lds_v*)(dst + base), 4, 0, 0);
        }
    };

    stage(0, ch0 + 0);
    stage(1, ch0 + 1);
    __syncthreads();

    float* outp = out + (size_t)b * CN * HW + (size_t)ch0 * HW + (size_t)h0 * WN + w;

    float oA[R], oB[R];   // round results, carried across the barrier

    for (int k = 0; k < ROUNDS; ++k) {
        const int m = 2 * k;                       // local channel of this round
        // 1) issue next-next staging (retires ~2 rounds from now)
        if (k + 1 < ROUNDS) {
            stage((m + 2) & 3, ch0 + m + 2);
            stage((m + 3) & 3, ch0 + m + 3);
        }
        // 2) store PREVIOUS round's results (issued ~2.5us before next barrier)
        if (k > 0) {
#pragma unroll
            for (int r = 0; r < R; ++r) {
                outp[(size_t)(m - 2) * HW + r * WN] = oA[r];
                outp[(size_t)(m - 1) * HW + r * WN] = oB[r];
            }
        }

        // 3) compute this round from LDS into registers
        const float* bufA = &lds[m & 3][0];
        const float* bufB = &lds[(m + 1) & 3][0];
        if (!dirty) {
#pragma unroll
            for (int r = 0; r < R; ++r) {
                const float Aa0 = bufA[sA[r]];
                const float Aa1 = bufA[sA[r] + 1];   // ds_read2_b32 pair
                const float Ab0 = bufA[sB[r]];
                const float Ab1 = bufA[sB[r] + 1];
                const float Ba0 = bufB[sA[r]];
                const float Ba1 = bufB[sA[r] + 1];
                const float Bb0 = bufB[sB[r]];
                const float Bb1 = bufB[sB[r] + 1];
                const float AIc = dx_[r] ? Aa1 : Aa0;
                const float AId = dx_[r] ? Ab1 : Ab0;
                const float BIc = dx_[r] ? Ba1 : Ba0;
                const float BId = dx_[r] ? Bb1 : Bb0;
                oA[r] = wa[r] * Aa0 + wb[r] * Ab0 + wc[r] * AIc + wd[r] * AId;
                oB[r] = wa[r] * Ba0 + wb[r] * Bb0 + wc[r] * BIc + wd[r] * BId;
            }
        } else {
            const float* pgA = imgb + (size_t)(ch0 + m) * HW;
            const float* pgB = imgb + (size_t)(ch0 + m + 1) * HW;
#pragma unroll
            for (int r = 0; r < R; ++r) {
                float Aa0 = bufA[sA[r]];
                float Aa1 = bufA[sA[r] + 1];
                float Ab0 = bufA[sB[r]];
                float Ab1 = bufA[sB[r] + 1];
                float Ba0 = bufB[sA[r]];
                float Ba1 = bufB[sA[r] + 1];
                float Bb0 = bufB[sB[r]];
                float Bb1 = bufB[sB[r] + 1];
                if (fb[r]) {
                    Aa0 = pgA[gA[r]];
                    Aa1 = pgA[gA[r] + dx_[r]];
                    Ab0 = pgA[gB[r]];
                    Ab1 = pgA[gB[r] + dx_[r]];
                    Ba0 = pgB[gA[r]];
                    Ba1 = pgB[gA[r] + dx_[r]];
                    Bb0 = pgB[gB[r]];
                    Bb1 = pgB[gB[r] + dx_[r]];
                }
                const float AIc = dx_[r] ? Aa1 : Aa0;
                const float AId = dx_[r] ? Ab1 : Ab0;
                const float BIc = dx_[r] ? Ba1 : Ba0;
                const float BId = dx_[r] ? Bb1 : Bb0;
                oA[r] = wa[r] * Aa0 + wb[r] * Ab0 + wc[r] * AIc + wd[r] * AId;
                oB[r] = wa[r] * Ba0 + wb[r] * Bb0 + wc[r] * BIc + wd[r] * BId;
            }
        }

        // 4) barrier: youngest VMEM (stage + prev stores) issued a full round ago
        __syncthreads();
    }

    // epilogue: store final round's results
#pragma unroll
    for (int r = 0; r < R; ++r) {
        outp[(size_t)(CLOOP - 2) * HW + r * WN] = oA[r];
        outp[(size_t)(CLOOP - 1) * HW + r * WN] = oB[r];
    }
}

extern "C" void kernel_launch(void* const* d_in, const int* in_sizes, int n_in,
                              void* d_out, int out_size, void* d_ws, size_t ws_size,
                              hipStream_t stream) {
    const float* img = (const float*)d_in[0];
    const float* flo = (const float*)d_in[1];
    float* out = (float*)d_out;

    const int grid = BN * (HN / R) * CSPLIT;   // 1024 blocks
    warp_kernel<<<grid, TPB, 0, stream>>>(img, flo, out);
}